// Round 15
// baseline (3076.746 us; speedup 1.0000x reference)
//
#include <hip/hip_runtime.h>
#include <hip/hip_bf16.h>

// Problem constants (from reference)
#define HH 512
#define WW 512
#define NN 8192
#define FF 2
#define BB 8
#define HW (HH * WW)      // 262144 pixels per batch image
#define NC (BB * NN)      // 65536 centers total

// Gaussian truncation: 3.8 sigma (validated r9/r11-r14, absmax 0.0039).
// Rf = 3.8*smax + 0.5 <= 15.7 < 16 = 2 strips of 8 rows: a strip's overlap
// set is exactly home strips [S-2, S+2] -> contiguous sorted-table slice.
#define NSIG 3.8f
#define SPI 64            // strips per image (8 rows each)
#define NBIN (BB * SPI)   // 512 sort bins (batch, home strip)
#define CBLK 256          // count/fill: 256 blocks x 256 threads = NC

// ---- dual-dtype input load: f32mode ? float : bf16 ----
__device__ __forceinline__ float ld(const void* p, int i, int f32mode) {
  if (f32mode) return ((const float*)p)[i];
  unsigned u = ((const unsigned short*)p)[i];
  return __uint_as_float(u << 16);
}

__device__ __forceinline__ float readlane_f(float v, int l) {
  return __uint_as_float(__builtin_amdgcn_readlane(__float_as_uint(v), l));
}

// Abramowitz & Stegun 7.1.26, |err| <= 1.5e-7.
__device__ __forceinline__ float erf_f(float x) {
  float ax = fabsf(x);
  float t = 1.0f / (1.0f + 0.3275911f * ax);
  float y = t * (0.254829592f +
           t * (-0.284496736f +
           t * (1.421413741f +
           t * (-1.453152027f +
           t * 1.061405429f))));
  y = 1.0f - y * __expf(-ax * ax);
  return copysignf(y, x);
}

__device__ __forceinline__ int home_strip(float row) {
  return min(max((int)floorf(row), 0), HH - 1) >> 3;
}

// Shared projection: center n of batch b -> (row, col).
__device__ __forceinline__ void project(const void* centers, const float* invT,
                                        int b, int n, int f32mode,
                                        float& row, float& col) {
  const float* Tb = invT + b * 16;
  float cx = ld(centers, 3 * n, f32mode);
  float cy = ld(centers, 3 * n + 1, f32mode);
  float cz = ld(centers, 3 * n + 2, f32mode);
  float p0 = Tb[0]  * cx + Tb[1]  * cy + Tb[2]  * cz + Tb[3];
  float p1 = Tb[4]  * cx + Tb[5]  * cy + Tb[6]  * cz + Tb[7];
  float p3 = Tb[12] * cx + Tb[13] * cy + Tb[14] * cz + Tb[15];
  float inv = 1.0f / p3;
  row = p0 * inv;
  col = p1 * inv;
}

// K1: detect dtype, then invert the 8 4x4 transforms (Gauss-Jordan), f32.
__global__ void k_inv(const void* __restrict__ T, float* __restrict__ invT,
                      int* __restrict__ flag) {
  int b = threadIdx.x;
  if (b >= BB) return;
  const float* Tf = (const float*)T;
  int f32mode = (fabsf(Tf[0] - 1.f) < 0.4f &&
                 fabsf(Tf[5] - 1.f) < 0.4f &&
                 fabsf(Tf[10] - 1.f) < 0.4f) ? 1 : 0;
  if (b == 0) *flag = f32mode;

  float a[4][8];
  for (int r = 0; r < 4; ++r)
    for (int c = 0; c < 4; ++c) {
      a[r][c] = ld(T, b * 16 + r * 4 + c, f32mode);
      a[r][4 + c] = (r == c) ? 1.0f : 0.0f;
    }
  for (int k = 0; k < 4; ++k) {
    int p = k; float best = fabsf(a[k][k]);
    for (int i = k + 1; i < 4; ++i) {
      float v = fabsf(a[i][k]);
      if (v > best) { best = v; p = i; }
    }
    if (p != k)
      for (int c = 0; c < 8; ++c) { float tmp = a[k][c]; a[k][c] = a[p][c]; a[p][c] = tmp; }
    float inv = 1.0f / a[k][k];
    for (int c = 0; c < 8; ++c) a[k][c] *= inv;
    for (int i = 0; i < 4; ++i) {
      if (i == k) continue;
      float f = a[i][k];
      for (int c = 0; c < 8; ++c) a[i][c] -= f * a[k][c];
    }
  }
  for (int r = 0; r < 4; ++r)
    for (int c = 0; c < 4; ++c)
      invT[b * 16 + r * 4 + c] = a[r][4 + c];
}

// K2: count centers per home strip, per block (each block = 256 consecutive
// centers of one batch -> 64 strip counters in LDS).
__global__ void __launch_bounds__(CBLK)
k_cnt(const void* __restrict__ centers, const float* __restrict__ invT,
      const int* __restrict__ flag, int* __restrict__ blkcnt) {
  __shared__ int cnt[SPI];
  int tid = threadIdx.x;
  if (tid < SPI) cnt[tid] = 0;
  __syncthreads();
  int idx = blockIdx.x * CBLK + tid;       // exact cover [0, NC)
  int f32mode = *flag;
  int b = idx >> 13, n = idx & (NN - 1);
  float row, col;
  project(centers, invT, b, n, f32mode, row, col);
  atomicAdd(&cnt[home_strip(row)], 1);     // int LDS atomic: native
  __syncthreads();
  if (tid < SPI) blkcnt[blockIdx.x * SPI + tid] = cnt[tid];
}

// K3: per-block counts -> absolute fill bases (in-place) + bin offsets.
// One block, 512 threads (= one per global bin).
__global__ void __launch_bounds__(NBIN)
k_scan(int* __restrict__ blkcnt, int* __restrict__ binoff) {
  __shared__ int tot[NBIN];
  int t = threadIdx.x;                     // global bin = b*64 + S
  int b = t >> 6, S = t & (SPI - 1);
  int acc = 0;
  for (int j = 0; j < 32; ++j) {           // 32 count-blocks per batch
    int idx = (b * 32 + j) * SPI + S;
    int c = blkcnt[idx]; blkcnt[idx] = acc; acc += c;
  }
  tot[t] = acc;
  __syncthreads();
  for (int d = 1; d < NBIN; d <<= 1) {
    int v = (t >= d) ? tot[t - d] : 0;
    __syncthreads();
    tot[t] += v;
    __syncthreads();
  }
  int base = tot[t] - acc;                 // exclusive prefix
  binoff[t] = base;
  if (t == NBIN - 1) binoff[NBIN] = tot[t];
  for (int j = 0; j < 32; ++j)
    blkcnt[(b * 32 + j) * SPI + S] += base;
}

// K4: recompute projection, build record, write at its sorted slot.
// tabA = {row, col, s0, w0}; tabB = {s1, w1, bubble_w, 0}.
__global__ void __launch_bounds__(CBLK)
k_fill(const void* __restrict__ centers, const void* __restrict__ scales,
       const void* __restrict__ weights, const void* __restrict__ bubble,
       const float* __restrict__ invT, const int* __restrict__ flag,
       const int* __restrict__ blkbase,
       float4* __restrict__ tabA, float4* __restrict__ tabB) {
  __shared__ int cur[SPI];
  int tid = threadIdx.x;
  if (tid < SPI) cur[tid] = blkbase[blockIdx.x * SPI + tid];
  __syncthreads();
  int idx = blockIdx.x * CBLK + tid;       // exact cover [0, NC)
  int f32mode = *flag;
  int b = idx >> 13, n = idx & (NN - 1);
  float row, col;
  project(centers, invT, b, n, f32mode, row, col);
  float4 A, Bv;
  A.x = row; A.y = col;
  A.z = ld(scales, 2 * n, f32mode);
  A.w = ld(weights, 2 * n, f32mode);
  Bv.x = ld(scales, 2 * n + 1, f32mode);
  Bv.y = ld(weights, 2 * n + 1, f32mode);
  Bv.z = ld(bubble, n, f32mode);
  Bv.w = 0.f;
  int pos = atomicAdd(&cur[home_strip(row)], 1);
  tabA[pos] = A;
  tabB[pos] = Bv;
}

// K5: ONE WAVE per 8x64 output tile (4096 waves). Scan the contiguous sorted
// slice of home strips [S-2, S+2] with affine coalesced loads; per-lane hit
// test; ballot; pop with readlane broadcast; accumulate in 8 VGPRs/lane
// (lane = column). NO atomics, NO LDS, NO syncthreads, NO img buffer —
// output written directly in the detected dtype.
__global__ void __launch_bounds__(256)
k_render(const float4* __restrict__ tabA, const float4* __restrict__ tabB,
         const int* __restrict__ binoff, const int* __restrict__ flag,
         void* __restrict__ out) {
  int wv = threadIdx.x >> 6, lane = threadIdx.x & 63;
  int tile = (blockIdx.x << 2) | wv;       // 4096 tiles
  int b = tile >> 9;
  int rem = tile & 511;
  int S = rem >> 3, ct = rem & 7;
  int row0 = S << 3, col0 = ct << 6;
  int f32mode = *flag;

  float acc[8];
#pragma unroll
  for (int k = 0; k < 8; ++k) acc[k] = 0.f;

  float colL = (float)(col0 + lane) - 0.5f;   // lane's col-low boundary
  float rowB = (float)(row0 + lane) - 0.5f;   // lanes 0..8: row boundaries
  float rA = (float)row0 - 0.5f, rZ = (float)(row0 + 7) + 0.5f;
  float cA = (float)col0 - 0.5f, cZ = (float)(col0 + 63) + 0.5f;

  int slo = max(S - 2, 0), shi = min(S + 2, SPI - 1);
  int lo = binoff[(b << 6) + slo];
  int hi = binoff[(b << 6) + shi + 1];

  for (int p = lo; p < hi; p += 64) {
    int my = p + lane;
    float4 A = make_float4(1e9f, 1e9f, 1.f, 0.f);
    float4 Bv = make_float4(1.f, 0.f, 0.f, 0.f);
    if (my < hi) { A = tabA[my]; Bv = tabB[my]; }

    // ---- per-lane hit tests on own record ----
    float row = A.x, col = A.y;
    float smax = fmaxf(A.z, Bv.x);
    float Rf = NSIG * smax + 0.5f;
    bool gh = (row + Rf >= rA) && (row - Rf <= rZ) &&
              (col + Rf >= cA) && (col - Rf <= cZ);
    int fr0 = (int)floorf(row), fc0 = (int)floorf(col);
    int rr0 = min(max(fr0, 0), HH - 1), rr1 = min(max(fr0 + 1, 0), HH - 1);
    int cc0 = min(max(fc0, 0), WW - 1), cc1 = min(max(fc0 + 1, 0), WW - 1);
    bool bh = (rr1 >= row0) && (rr0 <= row0 + 7) &&
              (cc1 >= col0) && (cc0 <= col0 + 63);
    unsigned long long mg = __ballot(gh);
    unsigned long long mb = __ballot(bh);
    unsigned long long m = mg | mb;

    while (m) {
      int src = (int)__builtin_ctzll(m);
      m &= m - 1;
      float prow = readlane_f(A.x, src), pcol = readlane_f(A.y, src);
      float ps0  = readlane_f(A.z, src), pW0  = readlane_f(A.w, src);
      float ps1  = readlane_f(Bv.x, src), pW1 = readlane_f(Bv.y, src);
      float pbw  = readlane_f(Bv.z, src);

      if ((mg >> src) & 1ull) {
        float rs0 = 0.70710678118f / ps0;
        float rs1 = 0.70710678118f / ps1;
        // lane's column profile (both features, weights folded)
        float x0 = (colL - pcol) * rs0;
        float pw0 = (erf_f(x0 + rs0) - erf_f(x0)) * (0.25f * pW0);
        float x1 = (colL - pcol) * rs1;
        float pw1 = (erf_f(x1 + rs1) - erf_f(x1)) * (0.25f * pW1);
        // row boundary erfs: lane j holds boundary j (j = 0..8 used)
        float E0 = erf_f((rowB - prow) * rs0);
        float E1 = erf_f((rowB - prow) * rs1);
        float d0[8], d1[8];
        float p0 = readlane_f(E0, 0), p1v = readlane_f(E1, 0);
#pragma unroll
        for (int k = 0; k < 8; ++k) {
          float n0 = readlane_f(E0, k + 1), n1 = readlane_f(E1, k + 1);
          d0[k] = n0 - p0; d1[k] = n1 - p1v;
          p0 = n0; p1v = n1;
        }
#pragma unroll
        for (int k = 0; k < 8; ++k)
          acc[k] += d0[k] * pw0 + d1[k] * pw1;
      }

      if ((mb >> src) & 1ull) {
        float rf = floorf(prow), cf = floorf(pcol);
        float fr = prow - rf, fc = pcol - cf;
        int pr0 = (int)rf, pc0 = (int)cf;
        int prr0 = min(max(pr0, 0), HH - 1), prr1 = min(max(pr0 + 1, 0), HH - 1);
        int pcc0 = min(max(pc0, 0), WW - 1), pcc1 = min(max(pc0 + 1, 0), WW - 1);
        int lc = col0 + lane;
        float vc = ((lc == pcc0) ? (1.f - fc) : 0.f) +
                   ((lc == pcc1) ? fc : 0.f);
        float v0 = pbw * (1.f - fr) * vc;    // row prr0
        float v1 = pbw * fr * vc;            // row prr1
        int k0 = prr0 - row0, k1 = prr1 - row0;
#pragma unroll
        for (int k = 0; k < 8; ++k)
          acc[k] += ((k == k0) ? v0 : 0.f) + ((k == k1) ? v1 : 0.f);
      }
    }
  }

  // ---- direct output write (each pixel owned by exactly one wave) ----
  size_t base = (size_t)b * HW + ((size_t)row0 << 9) + col0 + lane;
  if (f32mode) {
    float* o = (float*)out;
#pragma unroll
    for (int k = 0; k < 8; ++k) o[base + ((size_t)k << 9)] = acc[k];
  } else {
    unsigned short* o = (unsigned short*)out;
#pragma unroll
    for (int k = 0; k < 8; ++k) {
      __hip_bfloat16 h = __float2bfloat16(acc[k]);
      o[base + ((size_t)k << 9)] = *reinterpret_cast<unsigned short*>(&h);
    }
  }
}

extern "C" void kernel_launch(void* const* d_in, const int* in_sizes, int n_in,
                              void* d_out, int out_size, void* d_ws, size_t ws_size,
                              hipStream_t stream) {
  const void* T       = d_in[0];   // (B,4,4)
  const void* centers = d_in[1];   // (N,3)
  const void* scales  = d_in[2];   // (N,F)
  const void* weights = d_in[3];   // (N,F)
  const void* bubble  = d_in[4];   // (N,)

  char* ws = (char*)d_ws;
  size_t off = 0;
  float4* tabA  = (float4*)(ws + off); off += (size_t)NC * 16;          // 1 MB
  float4* tabB  = (float4*)(ws + off); off += (size_t)NC * 16;          // 1 MB
  int*    blkcnt= (int*)(ws + off);    off += (size_t)CBLK * SPI * 4;   // 64 KB
  int*    binoff= (int*)(ws + off);    off += (size_t)(NBIN + 1) * 4 + 12;
  off = (off + 15) & ~(size_t)15;
  float*  invT  = (float*)(ws + off);  off += (size_t)BB * 16 * 4;      // 512 B
  int*    flag  = (int*)(ws + off);

  k_inv   <<<1,    64,   0, stream>>>(T, invT, flag);
  k_cnt   <<<CBLK, CBLK, 0, stream>>>(centers, invT, flag, blkcnt);
  k_scan  <<<1,    NBIN, 0, stream>>>(blkcnt, binoff);
  k_fill  <<<CBLK, CBLK, 0, stream>>>(centers, scales, weights, bubble, invT, flag,
                                      blkcnt, tabA, tabB);
  k_render<<<1024, 256,  0, stream>>>(tabA, tabB, binoff, flag, d_out);
}

// Round 16
// 549.304 us; speedup vs baseline: 5.6012x; 5.6012x over previous
//
#include <hip/hip_runtime.h>
#include <hip/hip_bf16.h>

// Problem constants (from reference)
#define HH 512
#define WW 512
#define NN 8192
#define FF 2
#define BB 8
#define MM (NN * FF)      // 16384 splats per batch
#define HW (HH * WW)      // 262144 pixels per batch image
#define NC (BB * NN)      // 65536 centers total

// Gaussian truncation: 3.8 sigma (validated: r9/r11/r12/r14 pass, absmax
// 0.0039). Window width <= 2*(3.8*4+0.5)+1 -> at most 32 columns, which
// lets two image rows share one 64-lane atomic instruction.
#define NSIG 3.8f

// ---- dual-dtype input load: f32mode ? float : bf16 ----
__device__ __forceinline__ float ld(const void* p, int i, int f32mode) {
  if (f32mode) return ((const float*)p)[i];
  unsigned u = ((const unsigned short*)p)[i];
  return __uint_as_float(u << 16);
}

// readlane with wave-uniform index (SGPR path) — pure VALU/SALU, no LDS.
__device__ __forceinline__ float readlane_f(float v, int l) {
  return __uint_as_float(__builtin_amdgcn_readlane(__float_as_uint(v), l));
}

// Abramowitz & Stegun 7.1.26, |err| <= 1.5e-7.
__device__ __forceinline__ float erf_f(float x) {
  float ax = fabsf(x);
  float t = 1.0f / (1.0f + 0.3275911f * ax);
  float y = t * (0.254829592f +
           t * (-0.284496736f +
           t * (1.421413741f +
           t * (-1.453152027f +
           t * 1.061405429f))));
  y = 1.0f - y * __expf(-ax * ax);
  return copysignf(y, x);
}

// K1: detect dtype, then invert the 8 4x4 transforms (Gauss-Jordan), f32.
__global__ void k_inv(const void* __restrict__ T, float* __restrict__ invT,
                      int* __restrict__ flag) {
  int b = threadIdx.x;
  if (b >= BB) return;
  const float* Tf = (const float*)T;
  int f32mode = (fabsf(Tf[0] - 1.f) < 0.4f &&
                 fabsf(Tf[5] - 1.f) < 0.4f &&
                 fabsf(Tf[10] - 1.f) < 0.4f) ? 1 : 0;
  if (b == 0) *flag = f32mode;

  float a[4][8];
  for (int r = 0; r < 4; ++r)
    for (int c = 0; c < 4; ++c) {
      a[r][c] = ld(T, b * 16 + r * 4 + c, f32mode);
      a[r][4 + c] = (r == c) ? 1.0f : 0.0f;
    }
  for (int k = 0; k < 4; ++k) {
    int p = k; float best = fabsf(a[k][k]);
    for (int i = k + 1; i < 4; ++i) {
      float v = fabsf(a[i][k]);
      if (v > best) { best = v; p = i; }
    }
    if (p != k)
      for (int c = 0; c < 8; ++c) { float tmp = a[k][c]; a[k][c] = a[p][c]; a[p][c] = tmp; }
    float inv = 1.0f / a[k][k];
    for (int c = 0; c < 8; ++c) a[k][c] *= inv;
    for (int i = 0; i < 4; ++i) {
      if (i == k) continue;
      float f = a[i][k];
      for (int c = 0; c < 8; ++c) a[i][c] -= f * a[k][c];
    }
  }
  for (int r = 0; r < 4; ++r)
    for (int c = 0; c < 4; ++c)
      invT[b * 16 + r * 4 + c] = a[r][4 + c];
}

// K2: per-CENTER records (both features merged — same projected row/col):
// tabA[i] = {row, col, s0, w0}, tabB[i] = {s1, w1, bubble_w, 0}. Also zero img.
__global__ void k_table(const void* __restrict__ centers, const void* __restrict__ scales,
                        const void* __restrict__ weights, const void* __restrict__ bubble,
                        const float* __restrict__ invT, const int* __restrict__ flag,
                        float4* __restrict__ tabA, float4* __restrict__ tabB,
                        float4* __restrict__ img4) {
  int idx = blockIdx.x * blockDim.x + threadIdx.x;   // 512*256 = 131072 threads
  int stride = gridDim.x * blockDim.x;
  for (int j = idx; j < BB * HW / 4; j += stride)
    img4[j] = make_float4(0.f, 0.f, 0.f, 0.f);
  if (idx >= NC) return;
  int f32mode = *flag;
  int b = idx >> 13;           // NN = 2^13 centers per batch
  int n = idx & (NN - 1);
  const float* Tb = invT + b * 16;
  float cx = ld(centers, 3 * n, f32mode);
  float cy = ld(centers, 3 * n + 1, f32mode);
  float cz = ld(centers, 3 * n + 2, f32mode);
  float p0 = Tb[0]  * cx + Tb[1]  * cy + Tb[2]  * cz + Tb[3];
  float p1 = Tb[4]  * cx + Tb[5]  * cy + Tb[6]  * cz + Tb[7];
  float p3 = Tb[12] * cx + Tb[13] * cy + Tb[14] * cz + Tb[15];
  float inv = 1.0f / p3;
  float4 A, Bv;
  A.x = p0 * inv;              // row coordinate (A2P = 1)
  A.y = p1 * inv;              // col coordinate
  A.z = ld(scales, 2 * n, f32mode);       // s0
  A.w = ld(weights, 2 * n, f32mode);      // w0
  Bv.x = ld(scales, 2 * n + 1, f32mode);  // s1
  Bv.y = ld(weights, 2 * n + 1, f32mode); // w1
  Bv.z = ld(bubble, n, f32mode);          // bubble weight
  Bv.w = 0.f;
  tabA[idx] = A;
  tabB[idx] = Bv;
}

// K3: one wave per CENTER, LOOPED. SINGLE CHANGE vs r14 (475us): grid
// 2048 -> 1024 blocks, i.e. 16 centers/wave instead of 8. The r11/r13 fit
// (per-wave cost = n*C + D with end-of-wave atomic-drain D ~= C) predicts
// 475 * (16+1)/16 / ((8+1)/8) = ~449us: deeper amortization of the drain.
// Counter-signal: occupancy halves to ~27% — if aggregate atomic-stream
// parallelism mattered, this regresses instead.
__global__ void k_splat(const float4* __restrict__ tabA, const float4* __restrict__ tabB,
                        float* __restrict__ img) {
  int gid = blockIdx.x * blockDim.x + threadIdx.x;
  int lane = gid & 63;
  int nwaves = (gridDim.x * blockDim.x) >> 6;
  int wave = __builtin_amdgcn_readfirstlane(gid >> 6);

  int i = wave;
  float4 A = make_float4(0.f, 0.f, 1.f, 0.f);
  float4 Bv = make_float4(1.f, 0.f, 0.f, 0.f);
  if (i < NC) { A = tabA[i]; Bv = tabB[i]; }

  while (i < NC) {
    // ---- prefetch next center (uniform address -> s_load, lgkm queue) ----
    int in = i + nwaves;
    float4 An = A, Bn = Bv;
    if (in < NC) { An = tabA[in]; Bn = tabB[in]; }

    float row = A.x, col = A.y, s0 = A.z, w0 = A.w;
    float s1 = Bv.x, w1 = Bv.y, bw = Bv.z;
    float* imgb = img + ((size_t)(i >> 13) << 18);   // b*HW

    // ---- bubble point-mass (lanes 0-3) ----
    {
      float r0f = floorf(row), c0f = floorf(col);
      float fr = row - r0f, fc = col - c0f;
      int r0 = (int)r0f, c0 = (int)c0f;
      int rr0 = min(max(r0, 0), HH - 1), rr1 = min(max(r0 + 1, 0), HH - 1);
      int cc0 = min(max(c0, 0), WW - 1), cc1 = min(max(c0 + 1, 0), WW - 1);
      int rsel = (lane < 2) ? rr0 : rr1;
      int csel = (lane & 1) ? cc1 : cc0;
      float wr = (lane < 2) ? (1.f - fr) : fr;
      float wc = (lane & 1) ? fc : (1.f - fc);
      if (lane < 4)
        unsafeAtomicAdd(imgb + (rsel << 9) + csel, bw * wr * wc);
    }

    // ---- fused dual-feature separable gaussian, two-row-packed scatter ----
    float smax = fmaxf(s0, s1);
    float rs0 = 0.70710678118f / s0;         // 1/(s*sqrt(2))
    float rs1 = 0.70710678118f / s1;
    float Rf = NSIG * smax + 0.5f;
    int rlo = max(0, (int)ceilf(row - Rf));
    int rhi = min(HH - 1, (int)floorf(row + Rf));
    int clo = max(0, (int)ceilf(col - Rf));
    int chi = min(WW - 1, (int)floorf(col + Rf));
    if (rlo <= rhi && clo <= chi) {
      int nc = min(chi - clo + 1, 32);       // <= 32 by construction
      int nr = rhi - rlo + 1;
      int cl = lane & 31;                    // column offset within window
      int half = lane >> 5;                  // 0: row k, 1: row k+1
      // per-lane column profiles (weights folded); same in both halves
      float xc = (float)(clo + cl) - 0.5f - col;
      float x0 = xc * rs0;
      float pw0 = (erf_f(x0 + rs0) - erf_f(x0)) * (0.25f * w0);
      float x1 = xc * rs1;
      float pw1 = (erf_f(x1 + rs1) - erf_f(x1)) * (0.25f * w1);
      // per-lane row deltas: lane l holds delta of row rlo+l (l < nr <= 32)
      float yr = (float)(rlo + lane) - 0.5f - row;
      float y0 = yr * rs0;
      float Dh0 = erf_f(y0 + rs0) - erf_f(y0);
      float y1 = yr * rs1;
      float Dh1 = erf_f(y1 + rs1) - erf_f(y1);
      float* base = imgb + ((rlo + half) << 9) + clo + cl;
      for (int k = 0; k < nr; k += 2) {
        float d0a = readlane_f(Dh0, k), d0b = readlane_f(Dh0, k + 1);
        float d1a = readlane_f(Dh1, k), d1b = readlane_f(Dh1, k + 1);
        float d0 = half ? d0b : d0a;
        float d1 = half ? d1b : d1a;
        float val = d0 * pw0 + d1 * pw1;
        if (cl < nc && k + half < nr)
          unsafeAtomicAdd(base + (k << 9), val);
      }
    }

    i = in; A = An; Bv = Bn;
  }
}

// K4: f32 -> output conversion (bf16 packed or f32 passthrough, per detected mode).
__global__ void k_final(const float4* __restrict__ img4, const int* __restrict__ flag,
                        void* __restrict__ out) {
  int idx = blockIdx.x * blockDim.x + threadIdx.x;
  int stride = gridDim.x * blockDim.x;
  int f32mode = *flag;
  if (f32mode) {
    float4* o = (float4*)out;
    for (int j = idx; j < BB * HW / 4; j += stride)
      o[j] = img4[j];
  } else {
    ushort4* o = (ushort4*)out;
    for (int j = idx; j < BB * HW / 4; j += stride) {
      float4 v = img4[j];
      __hip_bfloat16 h0 = __float2bfloat16(v.x);
      __hip_bfloat16 h1 = __float2bfloat16(v.y);
      __hip_bfloat16 h2 = __float2bfloat16(v.z);
      __hip_bfloat16 h3 = __float2bfloat16(v.w);
      ushort4 t;
      t.x = *reinterpret_cast<unsigned short*>(&h0);
      t.y = *reinterpret_cast<unsigned short*>(&h1);
      t.z = *reinterpret_cast<unsigned short*>(&h2);
      t.w = *reinterpret_cast<unsigned short*>(&h3);
      o[j] = t;
    }
  }
}

extern "C" void kernel_launch(void* const* d_in, const int* in_sizes, int n_in,
                              void* d_out, int out_size, void* d_ws, size_t ws_size,
                              hipStream_t stream) {
  const void* T       = d_in[0];   // (B,4,4)
  const void* centers = d_in[1];   // (N,3)
  const void* scales  = d_in[2];   // (N,F)
  const void* weights = d_in[3];   // (N,F)
  const void* bubble  = d_in[4];   // (N,)

  char* ws = (char*)d_ws;
  size_t off = 0;
  float*  img  = (float*)(ws + off);  off += (size_t)BB * HW * 4;   // 8 MB
  float4* tabA = (float4*)(ws + off); off += (size_t)NC * 16;       // 1 MB
  float4* tabB = (float4*)(ws + off); off += (size_t)NC * 16;       // 1 MB
  float*  invT = (float*)(ws + off);  off += (size_t)BB * 16 * 4;   // 512 B
  int*    flag = (int*)(ws + off);

  k_inv<<<1, 64, 0, stream>>>(T, invT, flag);
  k_table<<<512, 256, 0, stream>>>(centers, scales, weights, bubble, invT, flag,
                                   tabA, tabB, (float4*)img);
  k_splat<<<1024, 256, 0, stream>>>(tabA, tabB, img);
  k_final<<<512, 256, 0, stream>>>((const float4*)img, flag, d_out);
}

// Round 17
// 538.241 us; speedup vs baseline: 5.7163x; 1.0206x over previous
//
#include <hip/hip_runtime.h>
#include <hip/hip_bf16.h>

// Problem constants (from reference)
#define HH 512
#define WW 512
#define NN 8192
#define FF 2
#define BB 8
#define HW (HH * WW)      // 262144 pixels per batch image
#define NC (BB * NN)      // 65536 centers total

// Gaussian truncation: 3.8 sigma (validated r9/r11/r12/r14/r16, absmax
// 0.0039). Window <= 32 cols -> two rows share one 64-lane atomic.
#define NSIG 3.8f

// ---- dual-dtype input load: f32mode ? float : bf16 ----
__device__ __forceinline__ float ld(const void* p, int i, int f32mode) {
  if (f32mode) return ((const float*)p)[i];
  unsigned u = ((const unsigned short*)p)[i];
  return __uint_as_float(u << 16);
}

// readlane with wave-uniform index (SGPR path) — pure VALU/SALU, no LDS.
__device__ __forceinline__ float readlane_f(float v, int l) {
  return __uint_as_float(__builtin_amdgcn_readlane(__float_as_uint(v), l));
}

// Abramowitz & Stegun 7.1.26, |err| <= 1.5e-7.
__device__ __forceinline__ float erf_f(float x) {
  float ax = fabsf(x);
  float t = 1.0f / (1.0f + 0.3275911f * ax);
  float y = t * (0.254829592f +
           t * (-0.284496736f +
           t * (1.421413741f +
           t * (-1.453152027f +
           t * 1.061405429f))));
  y = 1.0f - y * __expf(-ax * ax);
  return copysignf(y, x);
}

// K1: zero the f32 image (exactly one float4 per thread at 2048x256) and,
// in block 0, detect dtype + invert the 8 4x4 transforms (Gauss-Jordan).
// Replaces the old k_inv + k_table dispatches (the per-center table is
// obsolete: with 2048 splat blocks each wave owns ONE center index n and
// loops it across all 8 batches, so inputs are loaded once per wave).
__global__ void __launch_bounds__(256)
k_zero_inv(const void* __restrict__ T, float* __restrict__ invT,
           int* __restrict__ flag, float4* __restrict__ img4) {
  int gid = blockIdx.x * blockDim.x + threadIdx.x;
  img4[gid] = make_float4(0.f, 0.f, 0.f, 0.f);   // 524288 threads = 8 MB exact

  if (blockIdx.x == 0 && threadIdx.x < BB) {
    int b = threadIdx.x;
    const float* Tf = (const float*)T;
    int f32mode = (fabsf(Tf[0] - 1.f) < 0.4f &&
                   fabsf(Tf[5] - 1.f) < 0.4f &&
                   fabsf(Tf[10] - 1.f) < 0.4f) ? 1 : 0;
    if (b == 0) *flag = f32mode;

    float a[4][8];
    for (int r = 0; r < 4; ++r)
      for (int c = 0; c < 4; ++c) {
        a[r][c] = ld(T, b * 16 + r * 4 + c, f32mode);
        a[r][4 + c] = (r == c) ? 1.0f : 0.0f;
      }
    for (int k = 0; k < 4; ++k) {
      int p = k; float best = fabsf(a[k][k]);
      for (int i = k + 1; i < 4; ++i) {
        float v = fabsf(a[i][k]);
        if (v > best) { best = v; p = i; }
      }
      if (p != k)
        for (int c = 0; c < 8; ++c) { float tmp = a[k][c]; a[k][c] = a[p][c]; a[p][c] = tmp; }
      float inv = 1.0f / a[k][k];
      for (int c = 0; c < 8; ++c) a[k][c] *= inv;
      for (int i = 0; i < 4; ++i) {
        if (i == k) continue;
        float f = a[i][k];
        for (int c = 0; c < 8; ++c) a[i][c] -= f * a[k][c];
      }
    }
    for (int r = 0; r < 4; ++r)
      for (int c = 0; c < 4; ++c)
        invT[b * 16 + r * 4 + c] = a[r][4 + c];
  }
}

// K2: one wave per CENTER INDEX n (8192 waves); the wave loads its center's
// raw inputs ONCE (wave-uniform broadcast loads) and loops b = 0..7,
// projecting with invT[b] (s_load) and running the r14 fused dual-feature
// two-row-packed 3.8-sigma splat. Atomic pattern per wave is identical to
// r14's 475us config (stride-NN center walk).
__global__ void k_splat(const void* __restrict__ centers, const void* __restrict__ scales,
                        const void* __restrict__ weights, const void* __restrict__ bubble,
                        const float* __restrict__ invT, const int* __restrict__ flag,
                        float* __restrict__ img) {
  int gid = blockIdx.x * blockDim.x + threadIdx.x;
  int lane = gid & 63;
  int n = __builtin_amdgcn_readfirstlane(gid >> 6);   // wave id == center n
  int f32mode = *flag;

  // ---- wave-uniform center inputs (one load set per wave) ----
  float cx = ld(centers, 3 * n, f32mode);
  float cy = ld(centers, 3 * n + 1, f32mode);
  float cz = ld(centers, 3 * n + 2, f32mode);
  float s0 = ld(scales, 2 * n, f32mode);
  float s1 = ld(scales, 2 * n + 1, f32mode);
  float w0 = ld(weights, 2 * n, f32mode);
  float w1 = ld(weights, 2 * n + 1, f32mode);
  float bw = ld(bubble, n, f32mode);

  // scale-dependent constants (batch-invariant)
  float smax = fmaxf(s0, s1);
  float rs0 = 0.70710678118f / s0;           // 1/(s*sqrt(2))
  float rs1 = 0.70710678118f / s1;
  float Rf = NSIG * smax + 0.5f;

  for (int b = 0; b < BB; ++b) {
    const float* Tb = invT + b * 16;          // uniform addr -> s_load
    float p0 = Tb[0]  * cx + Tb[1]  * cy + Tb[2]  * cz + Tb[3];
    float p1 = Tb[4]  * cx + Tb[5]  * cy + Tb[6]  * cz + Tb[7];
    float p3 = Tb[12] * cx + Tb[13] * cy + Tb[14] * cz + Tb[15];
    float inv = 1.0f / p3;
    float row = p0 * inv, col = p1 * inv;
    float* imgb = img + ((size_t)b << 18);    // b*HW

    // ---- bubble point-mass (lanes 0-3) ----
    {
      float r0f = floorf(row), c0f = floorf(col);
      float fr = row - r0f, fc = col - c0f;
      int r0 = (int)r0f, c0 = (int)c0f;
      int rr0 = min(max(r0, 0), HH - 1), rr1 = min(max(r0 + 1, 0), HH - 1);
      int cc0 = min(max(c0, 0), WW - 1), cc1 = min(max(c0 + 1, 0), WW - 1);
      int rsel = (lane < 2) ? rr0 : rr1;
      int csel = (lane & 1) ? cc1 : cc0;
      float wr = (lane < 2) ? (1.f - fr) : fr;
      float wc = (lane & 1) ? fc : (1.f - fc);
      if (lane < 4)
        unsafeAtomicAdd(imgb + (rsel << 9) + csel, bw * wr * wc);
    }

    // ---- fused dual-feature separable gaussian, two-row-packed scatter ----
    int rlo = max(0, (int)ceilf(row - Rf));
    int rhi = min(HH - 1, (int)floorf(row + Rf));
    int clo = max(0, (int)ceilf(col - Rf));
    int chi = min(WW - 1, (int)floorf(col + Rf));
    if (rlo <= rhi && clo <= chi) {
      int nc = min(chi - clo + 1, 32);       // <= 32 by construction
      int nr = rhi - rlo + 1;
      int cl = lane & 31;                    // column offset within window
      int half = lane >> 5;                  // 0: row k, 1: row k+1
      // per-lane column profiles (weights folded); same in both halves
      float xc = (float)(clo + cl) - 0.5f - col;
      float x0 = xc * rs0;
      float pw0 = (erf_f(x0 + rs0) - erf_f(x0)) * (0.25f * w0);
      float x1 = xc * rs1;
      float pw1 = (erf_f(x1 + rs1) - erf_f(x1)) * (0.25f * w1);
      // per-lane row deltas: lane l holds delta of row rlo+l (l < nr <= 32)
      float yr = (float)(rlo + lane) - 0.5f - row;
      float y0 = yr * rs0;
      float Dh0 = erf_f(y0 + rs0) - erf_f(y0);
      float y1 = yr * rs1;
      float Dh1 = erf_f(y1 + rs1) - erf_f(y1);
      float* base = imgb + ((rlo + half) << 9) + clo + cl;
      for (int k = 0; k < nr; k += 2) {
        float d0a = readlane_f(Dh0, k), d0b = readlane_f(Dh0, k + 1);
        float d1a = readlane_f(Dh1, k), d1b = readlane_f(Dh1, k + 1);
        float d0 = half ? d0b : d0a;
        float d1 = half ? d1b : d1a;
        float val = d0 * pw0 + d1 * pw1;
        if (cl < nc && k + half < nr)
          unsafeAtomicAdd(base + (k << 9), val);
      }
    }
  }
}

// K3: f32 -> output conversion (bf16 packed or f32 passthrough, per detected mode).
__global__ void k_final(const float4* __restrict__ img4, const int* __restrict__ flag,
                        void* __restrict__ out) {
  int idx = blockIdx.x * blockDim.x + threadIdx.x;
  int stride = gridDim.x * blockDim.x;
  int f32mode = *flag;
  if (f32mode) {
    float4* o = (float4*)out;
    for (int j = idx; j < BB * HW / 4; j += stride)
      o[j] = img4[j];
  } else {
    ushort4* o = (ushort4*)out;
    for (int j = idx; j < BB * HW / 4; j += stride) {
      float4 v = img4[j];
      __hip_bfloat16 h0 = __float2bfloat16(v.x);
      __hip_bfloat16 h1 = __float2bfloat16(v.y);
      __hip_bfloat16 h2 = __float2bfloat16(v.z);
      __hip_bfloat16 h3 = __float2bfloat16(v.w);
      ushort4 t;
      t.x = *reinterpret_cast<unsigned short*>(&h0);
      t.y = *reinterpret_cast<unsigned short*>(&h1);
      t.z = *reinterpret_cast<unsigned short*>(&h2);
      t.w = *reinterpret_cast<unsigned short*>(&h3);
      o[j] = t;
    }
  }
}

extern "C" void kernel_launch(void* const* d_in, const int* in_sizes, int n_in,
                              void* d_out, int out_size, void* d_ws, size_t ws_size,
                              hipStream_t stream) {
  const void* T       = d_in[0];   // (B,4,4)
  const void* centers = d_in[1];   // (N,3)
  const void* scales  = d_in[2];   // (N,F)
  const void* weights = d_in[3];   // (N,F)
  const void* bubble  = d_in[4];   // (N,)

  char* ws = (char*)d_ws;
  size_t off = 0;
  float*  img  = (float*)(ws + off);  off += (size_t)BB * HW * 4;   // 8 MB
  float*  invT = (float*)(ws + off);  off += (size_t)BB * 16 * 4;   // 512 B
  int*    flag = (int*)(ws + off);

  k_zero_inv<<<2048, 256, 0, stream>>>(T, invT, flag, (float4*)img);
  k_splat   <<<2048, 256, 0, stream>>>(centers, scales, weights, bubble,
                                       invT, flag, img);
  k_final   <<<512,  256, 0, stream>>>((const float4*)img, flag, d_out);
}

// Round 19
// 537.585 us; speedup vs baseline: 5.7233x; 1.0012x over previous
//
#include <hip/hip_runtime.h>
#include <hip/hip_bf16.h>

// Problem constants (from reference)
#define HH 512
#define WW 512
#define NN 8192
#define FF 2
#define BB 8
#define HW (HH * WW)      // 262144 pixels per batch image
#define NC (BB * NN)      // 65536 centers total

// Gaussian truncation: 3.8 sigma (validated r9/r11/r12/r14/r16/r17, absmax
// 0.0039). Window <= 32 cols -> two rows share one 64-lane atomic.
#define NSIG 3.8f

// ---- dual-dtype input load: f32mode ? float : bf16 ----
__device__ __forceinline__ float ld(const void* p, int i, int f32mode) {
  if (f32mode) return ((const float*)p)[i];
  unsigned u = ((const unsigned short*)p)[i];
  return __uint_as_float(u << 16);
}

// readlane with wave-uniform index (SGPR path) — pure VALU/SALU, no LDS.
__device__ __forceinline__ float readlane_f(float v, int l) {
  return __uint_as_float(__builtin_amdgcn_readlane(__float_as_uint(v), l));
}

// Abramowitz & Stegun 7.1.26, |err| <= 1.5e-7.
__device__ __forceinline__ float erf_f(float x) {
  float ax = fabsf(x);
  float t = 1.0f / (1.0f + 0.3275911f * ax);
  float y = t * (0.254829592f +
           t * (-0.284496736f +
           t * (1.421413741f +
           t * (-1.453152027f +
           t * 1.061405429f))));
  y = 1.0f - y * __expf(-ax * ax);
  return copysignf(y, x);
}

// K1: zero the f32 image (exactly one float4 per thread at 2048x256) and,
// in block 0, detect dtype + invert the 8 4x4 transforms (Gauss-Jordan).
__global__ void __launch_bounds__(256)
k_zero_inv(const void* __restrict__ T, float* __restrict__ invT,
           int* __restrict__ flag, float4* __restrict__ img4) {
  int gid = blockIdx.x * blockDim.x + threadIdx.x;
  img4[gid] = make_float4(0.f, 0.f, 0.f, 0.f);   // 524288 threads = 8 MB exact

  if (blockIdx.x == 0 && threadIdx.x < BB) {
    int b = threadIdx.x;
    const float* Tf = (const float*)T;
    int f32mode = (fabsf(Tf[0] - 1.f) < 0.4f &&
                   fabsf(Tf[5] - 1.f) < 0.4f &&
                   fabsf(Tf[10] - 1.f) < 0.4f) ? 1 : 0;
    if (b == 0) *flag = f32mode;

    float a[4][8];
    for (int r = 0; r < 4; ++r)
      for (int c = 0; c < 4; ++c) {
        a[r][c] = ld(T, b * 16 + r * 4 + c, f32mode);
        a[r][4 + c] = (r == c) ? 1.0f : 0.0f;
      }
    for (int k = 0; k < 4; ++k) {
      int p = k; float best = fabsf(a[k][k]);
      for (int i = k + 1; i < 4; ++i) {
        float v = fabsf(a[i][k]);
        if (v > best) { best = v; p = i; }
      }
      if (p != k)
        for (int c = 0; c < 8; ++c) { float tmp = a[k][c]; a[k][c] = a[p][c]; a[p][c] = tmp; }
      float inv = 1.0f / a[k][k];
      for (int c = 0; c < 8; ++c) a[k][c] *= inv;
      for (int i = 0; i < 4; ++i) {
        if (i == k) continue;
        float f = a[i][k];
        for (int c = 0; c < 8; ++c) a[i][c] -= f * a[k][c];
      }
    }
    for (int r = 0; r < 4; ++r)
      for (int c = 0; c < 4; ++c)
        invT[b * 16 + r * 4 + c] = a[r][4 + c];
  }
}

// K2: one wave per CENTER INDEX n (8192 waves); the wave loads its center's
// raw inputs ONCE (wave-uniform broadcast loads) and loops b = 0..7,
// projecting with invT[b] (s_load) and running the fused dual-feature
// two-row-packed 3.8-sigma splat. 470us @ 54% occupancy — the established
// device-scope scatter-atomic floor for this shape (8 levers falsified).
__global__ void k_splat(const void* __restrict__ centers, const void* __restrict__ scales,
                        const void* __restrict__ weights, const void* __restrict__ bubble,
                        const float* __restrict__ invT, const int* __restrict__ flag,
                        float* __restrict__ img) {
  int gid = blockIdx.x * blockDim.x + threadIdx.x;
  int lane = gid & 63;
  int n = __builtin_amdgcn_readfirstlane(gid >> 6);   // wave id == center n
  int f32mode = *flag;

  // ---- wave-uniform center inputs (one load set per wave) ----
  float cx = ld(centers, 3 * n, f32mode);
  float cy = ld(centers, 3 * n + 1, f32mode);
  float cz = ld(centers, 3 * n + 2, f32mode);
  float s0 = ld(scales, 2 * n, f32mode);
  float s1 = ld(scales, 2 * n + 1, f32mode);
  float w0 = ld(weights, 2 * n, f32mode);
  float w1 = ld(weights, 2 * n + 1, f32mode);
  float bw = ld(bubble, n, f32mode);

  // scale-dependent constants (batch-invariant)
  float smax = fmaxf(s0, s1);
  float rs0 = 0.70710678118f / s0;           // 1/(s*sqrt(2))
  float rs1 = 0.70710678118f / s1;
  float Rf = NSIG * smax + 0.5f;

  for (int b = 0; b < BB; ++b) {
    const float* Tb = invT + b * 16;          // uniform addr -> s_load
    float p0 = Tb[0]  * cx + Tb[1]  * cy + Tb[2]  * cz + Tb[3];
    float p1 = Tb[4]  * cx + Tb[5]  * cy + Tb[6]  * cz + Tb[7];
    float p3 = Tb[12] * cx + Tb[13] * cy + Tb[14] * cz + Tb[15];
    float inv = 1.0f / p3;
    float row = p0 * inv, col = p1 * inv;
    float* imgb = img + ((size_t)b << 18);    // b*HW

    // ---- bubble point-mass (lanes 0-3) ----
    {
      float r0f = floorf(row), c0f = floorf(col);
      float fr = row - r0f, fc = col - c0f;
      int r0 = (int)r0f, c0 = (int)c0f;
      int rr0 = min(max(r0, 0), HH - 1), rr1 = min(max(r0 + 1, 0), HH - 1);
      int cc0 = min(max(c0, 0), WW - 1), cc1 = min(max(c0 + 1, 0), WW - 1);
      int rsel = (lane < 2) ? rr0 : rr1;
      int csel = (lane & 1) ? cc1 : cc0;
      float wr = (lane < 2) ? (1.f - fr) : fr;
      float wc = (lane & 1) ? fc : (1.f - fc);
      if (lane < 4)
        unsafeAtomicAdd(imgb + (rsel << 9) + csel, bw * wr * wc);
    }

    // ---- fused dual-feature separable gaussian, two-row-packed scatter ----
    int rlo = max(0, (int)ceilf(row - Rf));
    int rhi = min(HH - 1, (int)floorf(row + Rf));
    int clo = max(0, (int)ceilf(col - Rf));
    int chi = min(WW - 1, (int)floorf(col + Rf));
    if (rlo <= rhi && clo <= chi) {
      int nc = min(chi - clo + 1, 32);       // <= 32 by construction
      int nr = rhi - rlo + 1;
      int cl = lane & 31;                    // column offset within window
      int half = lane >> 5;                  // 0: row k, 1: row k+1
      // per-lane column profiles (weights folded); same in both halves
      float xc = (float)(clo + cl) - 0.5f - col;
      float x0 = xc * rs0;
      float pw0 = (erf_f(x0 + rs0) - erf_f(x0)) * (0.25f * w0);
      float x1 = xc * rs1;
      float pw1 = (erf_f(x1 + rs1) - erf_f(x1)) * (0.25f * w1);
      // per-lane row deltas: lane l holds delta of row rlo+l (l < nr <= 32)
      float yr = (float)(rlo + lane) - 0.5f - row;
      float y0 = yr * rs0;
      float Dh0 = erf_f(y0 + rs0) - erf_f(y0);
      float y1 = yr * rs1;
      float Dh1 = erf_f(y1 + rs1) - erf_f(y1);
      float* base = imgb + ((rlo + half) << 9) + clo + cl;
      for (int k = 0; k < nr; k += 2) {
        float d0a = readlane_f(Dh0, k), d0b = readlane_f(Dh0, k + 1);
        float d1a = readlane_f(Dh1, k), d1b = readlane_f(Dh1, k + 1);
        float d0 = half ? d0b : d0a;
        float d1 = half ? d1b : d1a;
        float val = d0 * pw0 + d1 * pw1;
        if (cl < nc && k + half < nr)
          unsafeAtomicAdd(base + (k << 9), val);
      }
    }
  }
}

// K3: f32 -> output conversion (bf16 packed or f32 passthrough, per detected mode).
__global__ void k_final(const float4* __restrict__ img4, const int* __restrict__ flag,
                        void* __restrict__ out) {
  int idx = blockIdx.x * blockDim.x + threadIdx.x;
  int stride = gridDim.x * blockDim.x;
  int f32mode = *flag;
  if (f32mode) {
    float4* o = (float4*)out;
    for (int j = idx; j < BB * HW / 4; j += stride)
      o[j] = img4[j];
  } else {
    ushort4* o = (ushort4*)out;
    for (int j = idx; j < BB * HW / 4; j += stride) {
      float4 v = img4[j];
      __hip_bfloat16 h0 = __float2bfloat16(v.x);
      __hip_bfloat16 h1 = __float2bfloat16(v.y);
      __hip_bfloat16 h2 = __float2bfloat16(v.z);
      __hip_bfloat16 h3 = __float2bfloat16(v.w);
      ushort4 t;
      t.x = *reinterpret_cast<unsigned short*>(&h0);
      t.y = *reinterpret_cast<unsigned short*>(&h1);
      t.z = *reinterpret_cast<unsigned short*>(&h2);
      t.w = *reinterpret_cast<unsigned short*>(&h3);
      o[j] = t;
    }
  }
}

extern "C" void kernel_launch(void* const* d_in, const int* in_sizes, int n_in,
                              void* d_out, int out_size, void* d_ws, size_t ws_size,
                              hipStream_t stream) {
  const void* T       = d_in[0];   // (B,4,4)
  const void* centers = d_in[1];   // (N,3)
  const void* scales  = d_in[2];   // (N,F)
  const void* weights = d_in[3];   // (N,F)
  const void* bubble  = d_in[4];   // (N,)

  char* ws = (char*)d_ws;
  size_t off = 0;
  float*  img  = (float*)(ws + off);  off += (size_t)BB * HW * 4;   // 8 MB
  float*  invT = (float*)(ws + off);  off += (size_t)BB * 16 * 4;   // 512 B
  int*    flag = (int*)(ws + off);

  k_zero_inv<<<2048, 256, 0, stream>>>(T, invT, flag, (float4*)img);
  k_splat   <<<2048, 256, 0, stream>>>(centers, scales, weights, bubble,
                                       invT, flag, img);
  k_final   <<<512,  256, 0, stream>>>((const float4*)img, flag, d_out);
}